// Round 8
// baseline (317.813 us; speedup 1.0000x reference)
//
#include <hip/hip_runtime.h>
#include <hip/hip_bf16.h>
#include <cstddef>

#define BB 1024
#define TT 4096
#define LL 30
#define HH 32
// P = 2, DT = 1.0

typedef int v2i __attribute__((ext_vector_type(2)));

// ---- fast branch-free tanh: abs err ~1e-7 ----
__device__ __forceinline__ float tanh_fast(float x) {
    float t = __builtin_amdgcn_exp2f(x * 2.8853900817779268f);
    float r = __builtin_amdgcn_rcpf(t + 1.0f);
    return fmaf(-2.0f, r, 1.0f);
}

// ---- DPP add step (within-16-lane rows) ----
template <int CTRL>
__device__ __forceinline__ float dpp_add_f(float x) {
    int yi = __builtin_amdgcn_update_dpp(0, __float_as_int(x), CTRL, 0xF, 0xF, true);
    return x + __int_as_float(yi);
}

// Layout B3 (correctness-proven R4-R7): unit j = (lane&15) + 16*(lane>>5),
// chain c = (lane>>4)&1. Chain c occupies rows {c, c+2} (lane^32 apart).
// chain_reduce: sum q0,q1 over each chain's 32 lanes, broadcast both sums to
// all of that chain's lanes. 7 levels (swap, 5 adds, swap) — minimal.
__device__ __forceinline__ void chain_reduce(float q0, float q1, float& S0, float& S1) {
    v2i sw = __builtin_amdgcn_permlane32_swap(__float_as_int(q0), __float_as_int(q1), false, false);
    float C = __int_as_float(sw.x) + __int_as_float(sw.y);
    C = dpp_add_f<0xB1>(C);    // quad_perm xor1
    C = dpp_add_f<0x4E>(C);    // quad_perm xor2
    C = dpp_add_f<0x141>(C);   // row_half_mirror
    C = dpp_add_f<0x140>(C);   // row_mirror
    v2i pq = __builtin_amdgcn_permlane32_swap(__float_as_int(C), __float_as_int(C), false, false);
    S0 = __int_as_float(pq.x);
    S1 = __int_as_float(pq.y);
}

// Fused kernel: encoder + sequential Euler scan + epilogue (kappa -> a -> xhat).
// 32 lanes per chain (2 trans/step), 2 chains/wave, 512 waves.
// phi prefetch is issued at burst start and PINNED there with sched_barrier(0)
// so the compiler cannot sink it to its use at burst end (R7's regression).
__global__ __launch_bounds__(64) void ode_scan_kernel(
    const float* __restrict__ x, const float* __restrict__ phi,
    const float* __restrict__ ew1, const float* __restrict__ eb1,
    const float* __restrict__ ew2, const float* __restrict__ eb2,
    const float* __restrict__ fw1, const float* __restrict__ fb1,
    const float* __restrict__ fw2, const float* __restrict__ fb2,
    float* __restrict__ xhat, float* __restrict__ aout,
    float* __restrict__ zout)
{
    const int tid = threadIdx.x;
    const int g   = tid & 15;                     // position within row
    const int c   = (tid >> 4) & 1;               // chain within wave
    const int j   = g + ((tid >> 5) << 4);        // hidden unit (0..31)
    const int b   = blockIdx.x * 2 + c;           // batch chain

    // ---- f-MLP weights, prescaled/folded ----
    const float KE  = 2.8853900817779268f;        // 2*log2(e)
    const float w1  = fw1[j] * KE;
    const float w1b = fw1[HH + j] * KE;
    const float b1  = fb1[j] * KE;
    const float w20 = fw2[j * 2 + 0], w21 = fw2[j * 2 + 1];
    const float n0  = -2.0f * w20,    n1  = -2.0f * w21;
    const float base0 = w20 + fb2[0] * (1.0f / 32.0f);  // reduce spans 32 lanes
    const float base1 = w21 + fb2[1] * (1.0f / 32.0f);

    // ---------------- encoder: z0 = tanh(x[:, :30] @ ew1 + eb1) @ ew2 + eb2
    float z1, z2;
    {
        float s = eb1[j];
        const float* xb = x + (size_t)b * TT;
        #pragma unroll
        for (int l = 0; l < LL; ++l)
            s = fmaf(xb[l], ew1[l * HH + j], s);
        float h = tanh_fast(s);
        float S0, S1;
        chain_reduce(h * ew2[j * 2 + 0], h * ew2[j * 2 + 1], S0, S1);
        z1 = S0 + eb2[0];
        z2 = S1 + eb2[1];
    }

    // running first-layer preactivation for this lane's unit j
    float aa = fmaf(z2, w1b, fmaf(z1, w1, b1));

    // one Euler step. Chain (13 levels): exp->add->rcp->fma->swap->add->dpp4->swap->fma->fma.
    #define STEP() do {                                          \
        float ee = __builtin_amdgcn_exp2f(aa);                   \
        float rr = __builtin_amdgcn_rcpf(ee + 1.0f);             \
        float q0 = fmaf(rr, n0, base0);                          \
        float q1 = fmaf(rr, n1, base1);                          \
        float S0, S1;                                            \
        chain_reduce(q0, q1, S0, S1);                            \
        aa = fmaf(S1, w1b, fmaf(S0, w1, aa));                    \
        z1 += S0; z2 += S1;                                      \
    } while (0)

    #define CAPTURE(k) do {                                      \
        bool cp = (g == (k));                                    \
        h1 = cp ? z1 : h1;                                       \
        h2 = cp ? z2 : h2;                                       \
    } while (0)

    // Fused epilogue for one burst: lane g owns timestep 16*bb+g of its chain.
    // kappa = tanh(z); a = (k1*(1-k2), k2); xhat = a . phi (0 for t<2).
    #define EPILOG(is_first) do {                                \
        float K1 = tanh_fast(h1), K2 = tanh_fast(h2);            \
        float A1 = K1 * (1.0f - K2), A2 = K2;                    \
        float xh = fmaf(A2, ph.y, A1 * ph.x);                    \
        if ((is_first) && g < 2) xh = 0.0f;                      \
        if (storer) {                                            \
            float2 vz; vz.x = h1; vz.y = h2; *(float2*)zp = vz;  \
            float2 va; va.x = A1; va.y = A2; *(float2*)ap = va;  \
            *xp = xh;                                            \
        }                                                        \
    } while (0)

    // history regs: lane with g==k holds timeline entry (16*burst + k) of its
    // own chain; rows 2,3 duplicate rows 0,1 (not stored).
    float h1 = z1, h2 = z2;
    float*       zp = zout + (size_t)b * TT * 2 + g * 2;
    float*       ap = aout + (size_t)b * TT * 2 + g * 2;
    float*       xp = xhat + (size_t)b * TT + g;
    const float* pp = phi  + (size_t)b * TT * 2 + g * 2;
    const bool storer = (tid < 32);   // row0 -> chain0, row1 -> chain1
    float2 ph;

    // ---- prologue burst: entries 1..15 (h init covers entry 0 at g==0)
    ph = *(const float2*)pp;          // issue early...
    __builtin_amdgcn_sched_barrier(0);  // ...and pin: no sinking past this point
    #pragma unroll
    for (int k = 1; k < 16; ++k) { STEP(); CAPTURE(k); }
    EPILOG(true);
    zp += 32; ap += 32; xp += 16; pp += 32;

    // ---- main loop: 255 bursts x 16 steps
    for (int bb = 1; bb < 256; ++bb) {
        ph = *(const float2*)pp;      // prefetch for THIS burst's epilogue
        __builtin_amdgcn_sched_barrier(0);  // pin issue at burst start (~2500 cyc ahead of use)
        #pragma unroll
        for (int k = 0; k < 16; ++k) { STEP(); CAPTURE(k); }
        EPILOG(false);
        zp += 32; ap += 32; xp += 16; pp += 32;
    }
    #undef STEP
    #undef CAPTURE
    #undef EPILOG
}

extern "C" void kernel_launch(void* const* d_in, const int* in_sizes, int n_in,
                              void* d_out, int out_size, void* d_ws, size_t ws_size,
                              hipStream_t stream) {
    const float* x    = (const float*)d_in[0];
    const float* phi  = (const float*)d_in[1];
    const float* ew1  = (const float*)d_in[2];
    const float* eb1  = (const float*)d_in[3];
    const float* ew2  = (const float*)d_in[4];
    const float* eb2  = (const float*)d_in[5];
    const float* fw1  = (const float*)d_in[6];
    const float* fb1  = (const float*)d_in[7];
    const float* fw2  = (const float*)d_in[8];
    const float* fb2  = (const float*)d_in[9];

    float* out  = (float*)d_out;
    float* xhat = out;                          // (B, T)
    float* a    = out + (size_t)BB * TT;        // (B, T, 2)
    float* z    = out + (size_t)BB * TT * 3;    // (B, T, 2)

    // 512 blocks x 64 threads: 1 wave/block, 2 chains/wave — single fused kernel
    ode_scan_kernel<<<512, 64, 0, stream>>>(x, phi, ew1, eb1, ew2, eb2,
                                            fw1, fb1, fw2, fb2, xhat, a, z);
}

// Round 9
// 278.162 us; speedup vs baseline: 1.1425x; 1.1425x over previous
//
#include <hip/hip_runtime.h>
#include <hip/hip_bf16.h>
#include <cstddef>

#define BB 1024
#define TT 4096
#define LL 30
#define HH 32
// P = 2, DT = 1.0

typedef int v2i __attribute__((ext_vector_type(2)));

// ---- fast branch-free tanh: abs err ~1e-7 ----
__device__ __forceinline__ float tanh_fast(float x) {
    float t = __builtin_amdgcn_exp2f(x * 2.8853900817779268f);
    float r = __builtin_amdgcn_rcpf(t + 1.0f);
    return fmaf(-2.0f, r, 1.0f);
}

// ---- DPP add step (within-16-lane rows) ----
template <int CTRL>
__device__ __forceinline__ float dpp_add_f(float x) {
    int yi = __builtin_amdgcn_update_dpp(0, __float_as_int(x), CTRL, 0xF, 0xF, true);
    return x + __int_as_float(yi);
}

// Layout B3 (correctness-proven R4-R8): unit j = (lane&15) + 16*(lane>>5),
// chain c = (lane>>4)&1. Chain c occupies rows {c, c+2} (lane^32 apart).
// chain_reduce: sum q0,q1 over each chain's 32 lanes, broadcast both sums to
// all of that chain's lanes. 7 levels (swap, 5 adds, swap) — minimal.
__device__ __forceinline__ void chain_reduce(float q0, float q1, float& S0, float& S1) {
    v2i sw = __builtin_amdgcn_permlane32_swap(__float_as_int(q0), __float_as_int(q1), false, false);
    float C = __int_as_float(sw.x) + __int_as_float(sw.y);
    C = dpp_add_f<0xB1>(C);    // quad_perm xor1
    C = dpp_add_f<0x4E>(C);    // quad_perm xor2
    C = dpp_add_f<0x141>(C);   // row_half_mirror
    C = dpp_add_f<0x140>(C);   // row_mirror
    v2i pq = __builtin_amdgcn_permlane32_swap(__float_as_int(C), __float_as_int(C), false, false);
    S0 = __int_as_float(pq.x);
    S1 = __int_as_float(pq.y);
}

// Kernel 1: encoder + sequential Euler scan + a-epilogue (NO loads in the
// scan loop — loads were R7/R8's regression; stores are fire-and-forget).
// 32 lanes per chain (2 trans/step), 2 chains/wave, 512 waves.
// Running-preactivation recurrence keeps z-updates/capture off the chain.
__global__ __launch_bounds__(64) void ode_scan_kernel(
    const float* __restrict__ x,
    const float* __restrict__ ew1, const float* __restrict__ eb1,
    const float* __restrict__ ew2, const float* __restrict__ eb2,
    const float* __restrict__ fw1, const float* __restrict__ fb1,
    const float* __restrict__ fw2, const float* __restrict__ fb2,
    float* __restrict__ aout, float* __restrict__ zout)
{
    const int tid = threadIdx.x;
    const int g   = tid & 15;                     // position within row
    const int c   = (tid >> 4) & 1;               // chain within wave
    const int j   = g + ((tid >> 5) << 4);        // hidden unit (0..31)
    const int b   = blockIdx.x * 2 + c;           // batch chain

    // ---- f-MLP weights, prescaled/folded ----
    const float KE  = 2.8853900817779268f;        // 2*log2(e)
    const float w1  = fw1[j] * KE;
    const float w1b = fw1[HH + j] * KE;
    const float b1  = fb1[j] * KE;
    const float w20 = fw2[j * 2 + 0], w21 = fw2[j * 2 + 1];
    const float n0  = -2.0f * w20,    n1  = -2.0f * w21;
    const float base0 = w20 + fb2[0] * (1.0f / 32.0f);  // reduce spans 32 lanes
    const float base1 = w21 + fb2[1] * (1.0f / 32.0f);

    // ---------------- encoder: z0 = tanh(x[:, :30] @ ew1 + eb1) @ ew2 + eb2
    float z1, z2;
    {
        float s = eb1[j];
        const float* xb = x + (size_t)b * TT;
        #pragma unroll
        for (int l = 0; l < LL; ++l)
            s = fmaf(xb[l], ew1[l * HH + j], s);
        float h = tanh_fast(s);
        float S0, S1;
        chain_reduce(h * ew2[j * 2 + 0], h * ew2[j * 2 + 1], S0, S1);
        z1 = S0 + eb2[0];
        z2 = S1 + eb2[1];
    }

    // running first-layer preactivation for this lane's unit j
    float aa = fmaf(z2, w1b, fmaf(z1, w1, b1));

    // one Euler step. Chain (13 levels): exp->add->rcp->fma->swap->add->dpp4->swap->fma->fma.
    #define STEP() do {                                          \
        float ee = __builtin_amdgcn_exp2f(aa);                   \
        float rr = __builtin_amdgcn_rcpf(ee + 1.0f);             \
        float q0 = fmaf(rr, n0, base0);                          \
        float q1 = fmaf(rr, n1, base1);                          \
        float S0, S1;                                            \
        chain_reduce(q0, q1, S0, S1);                            \
        aa = fmaf(S1, w1b, fmaf(S0, w1, aa));                    \
        z1 += S0; z2 += S1;                                      \
    } while (0)

    #define CAPTURE(k) do {                                      \
        bool cp = (g == (k));                                    \
        h1 = cp ? z1 : h1;                                       \
        h2 = cp ? z2 : h2;                                       \
    } while (0)

    // Burst epilogue (store-only, off-chain): z and a = (k1*(1-k2), k2),
    // kappa = tanh(z). Lane g owns timestep 16*burst+g of its chain.
    #define EPILOG() do {                                        \
        float K1 = tanh_fast(h1), K2 = tanh_fast(h2);            \
        float A1 = K1 * (1.0f - K2), A2 = K2;                    \
        if (storer) {                                            \
            float2 vz; vz.x = h1; vz.y = h2; *(float2*)zp = vz;  \
            float2 va; va.x = A1; va.y = A2; *(float2*)ap = va;  \
        }                                                        \
    } while (0)

    // history regs: lane with g==k holds timeline entry (16*burst + k) of its
    // own chain; rows 2,3 duplicate rows 0,1 (not stored).
    float h1 = z1, h2 = z2;
    float* zp = zout + (size_t)b * TT * 2 + g * 2;
    float* ap = aout + (size_t)b * TT * 2 + g * 2;
    const bool storer = (tid < 32);   // row0 -> chain0, row1 -> chain1

    // ---- prologue burst: entries 1..15 (h init covers entry 0 at g==0)
    #pragma unroll
    for (int k = 1; k < 16; ++k) { STEP(); CAPTURE(k); }
    EPILOG();
    zp += 32; ap += 32;

    // ---- main loop: 255 bursts x 16 steps
    for (int bb = 1; bb < 256; ++bb) {
        #pragma unroll
        for (int k = 0; k < 16; ++k) { STEP(); CAPTURE(k); }
        EPILOG();
        zp += 32; ap += 32;
    }
    #undef STEP
    #undef CAPTURE
    #undef EPILOG
}

// Kernel 2: xhat only — pure streaming, a (just written, L3-hot) + phi.
// xhat[b,t] = a1*phi0 + a2*phi1, zero for t < 2.
__global__ __launch_bounds__(256) void xhat_kernel(
    const float* __restrict__ phi, const float* __restrict__ a,
    float* __restrict__ xhat)
{
    const int idx = blockIdx.x * blockDim.x + threadIdx.x;
    const int pos = idx * 2;                    // position pair (same b; t0 even)
    const int t0  = pos & (TT - 1);

    float4 av = *(const float4*)(a   + (size_t)pos * 2);
    float4 pv = *(const float4*)(phi + (size_t)pos * 2);

    float x0 = (t0 >= 2) ? fmaf(av.y, pv.y, av.x * pv.x) : 0.0f;
    float x1 = (t0 >= 2) ? fmaf(av.w, pv.w, av.z * pv.z)
                         : ((t0 + 1 >= 2) ? fmaf(av.w, pv.w, av.z * pv.z) : 0.0f);
    float2 xv; xv.x = x0; xv.y = x1;
    *(float2*)(xhat + pos) = xv;
}

extern "C" void kernel_launch(void* const* d_in, const int* in_sizes, int n_in,
                              void* d_out, int out_size, void* d_ws, size_t ws_size,
                              hipStream_t stream) {
    const float* x    = (const float*)d_in[0];
    const float* phi  = (const float*)d_in[1];
    const float* ew1  = (const float*)d_in[2];
    const float* eb1  = (const float*)d_in[3];
    const float* ew2  = (const float*)d_in[4];
    const float* eb2  = (const float*)d_in[5];
    const float* fw1  = (const float*)d_in[6];
    const float* fb1  = (const float*)d_in[7];
    const float* fw2  = (const float*)d_in[8];
    const float* fb2  = (const float*)d_in[9];

    float* out  = (float*)d_out;
    float* xhat = out;                          // (B, T)
    float* a    = out + (size_t)BB * TT;        // (B, T, 2)
    float* z    = out + (size_t)BB * TT * 3;    // (B, T, 2)

    // 512 blocks x 64 threads: 1 wave/block, 2 chains/wave — no loads in loop
    ode_scan_kernel<<<512, 64, 0, stream>>>(x, ew1, eb1, ew2, eb2,
                                            fw1, fb1, fw2, fb2, a, z);

    const int total_pairs = (BB * TT) / 2;
    xhat_kernel<<<total_pairs / 256, 256, 0, stream>>>(phi, a, xhat);
}

// Round 10
// 275.116 us; speedup vs baseline: 1.1552x; 1.0111x over previous
//
#include <hip/hip_runtime.h>
#include <hip/hip_bf16.h>
#include <cstddef>

#define BB 1024
#define TT 4096
#define LL 30
#define HH 32
// P = 2, DT = 1.0

typedef int v2i __attribute__((ext_vector_type(2)));

// ---- fast branch-free tanh: abs err ~1e-7 ----
__device__ __forceinline__ float tanh_fast(float x) {
    float t = __builtin_amdgcn_exp2f(x * 2.8853900817779268f);
    float r = __builtin_amdgcn_rcpf(t + 1.0f);
    return fmaf(-2.0f, r, 1.0f);
}

// ---- DPP add step (within-16-lane rows) ----
template <int CTRL>
__device__ __forceinline__ float dpp_add_f(float x) {
    int yi = __builtin_amdgcn_update_dpp(0, __float_as_int(x), CTRL, 0xF, 0xF, true);
    return x + __int_as_float(yi);
}

// Layout B3 (correctness-proven R4-R9): unit j = (lane&15) + 16*(lane>>5),
// chain c = (lane>>4)&1. Chain c occupies rows {c, c+2} (lane^32 apart).
// chain_reduce: sum q0,q1 over each chain's 32 lanes, broadcast both sums to
// all of that chain's lanes. 7 levels (swap, 5 adds, swap) — information-
// theoretic minimum for a 32-way sum + cross-row movement in this layout.
__device__ __forceinline__ void chain_reduce(float q0, float q1, float& S0, float& S1) {
    v2i sw = __builtin_amdgcn_permlane32_swap(__float_as_int(q0), __float_as_int(q1), false, false);
    float C = __int_as_float(sw.x) + __int_as_float(sw.y);
    C = dpp_add_f<0xB1>(C);    // quad_perm xor1
    C = dpp_add_f<0x4E>(C);    // quad_perm xor2
    C = dpp_add_f<0x141>(C);   // row_half_mirror
    C = dpp_add_f<0x140>(C);   // row_mirror
    v2i pq = __builtin_amdgcn_permlane32_swap(__float_as_int(C), __float_as_int(C), false, false);
    S0 = __int_as_float(pq.x);
    S1 = __int_as_float(pq.y);
}

// Kernel 1: encoder + sequential Euler scan (R6 configuration — best measured).
// 32 lanes per chain (2 trans/step), 2 chains/wave, 512 waves.
// NO loads in the scan loop (R7/R8 regression); stores are fire-and-forget.
// Running-preactivation recurrence keeps z-updates/capture off the 13-level
// dependent chain: exp->add->rcp->fma->swap->add->dpp4->swap->fma->fma.
__global__ __launch_bounds__(64) void ode_scan_kernel(
    const float* __restrict__ x,
    const float* __restrict__ ew1, const float* __restrict__ eb1,
    const float* __restrict__ ew2, const float* __restrict__ eb2,
    const float* __restrict__ fw1, const float* __restrict__ fb1,
    const float* __restrict__ fw2, const float* __restrict__ fb2,
    float* __restrict__ zout)
{
    const int tid = threadIdx.x;
    const int g   = tid & 15;                     // position within row
    const int c   = (tid >> 4) & 1;               // chain within wave
    const int j   = g + ((tid >> 5) << 4);        // hidden unit (0..31)
    const int b   = blockIdx.x * 2 + c;           // batch chain

    // ---- f-MLP weights, prescaled/folded ----
    const float KE  = 2.8853900817779268f;        // 2*log2(e)
    const float w1  = fw1[j] * KE;
    const float w1b = fw1[HH + j] * KE;
    const float b1  = fb1[j] * KE;
    const float w20 = fw2[j * 2 + 0], w21 = fw2[j * 2 + 1];
    const float n0  = -2.0f * w20,    n1  = -2.0f * w21;
    const float base0 = w20 + fb2[0] * (1.0f / 32.0f);  // reduce spans 32 lanes
    const float base1 = w21 + fb2[1] * (1.0f / 32.0f);

    // ---------------- encoder: z0 = tanh(x[:, :30] @ ew1 + eb1) @ ew2 + eb2
    float z1, z2;
    {
        float s = eb1[j];
        const float* xb = x + (size_t)b * TT;
        #pragma unroll
        for (int l = 0; l < LL; ++l)
            s = fmaf(xb[l], ew1[l * HH + j], s);
        float h = tanh_fast(s);
        float S0, S1;
        chain_reduce(h * ew2[j * 2 + 0], h * ew2[j * 2 + 1], S0, S1);
        z1 = S0 + eb2[0];
        z2 = S1 + eb2[1];
    }

    // running first-layer preactivation for this lane's unit j
    float aa = fmaf(z2, w1b, fmaf(z1, w1, b1));

    // one Euler step (13 dependent levels; z updates + capture off-chain)
    #define STEP() do {                                          \
        float ee = __builtin_amdgcn_exp2f(aa);                   \
        float rr = __builtin_amdgcn_rcpf(ee + 1.0f);             \
        float q0 = fmaf(rr, n0, base0);                          \
        float q1 = fmaf(rr, n1, base1);                          \
        float S0, S1;                                            \
        chain_reduce(q0, q1, S0, S1);                            \
        aa = fmaf(S1, w1b, fmaf(S0, w1, aa));                    \
        z1 += S0; z2 += S1;                                      \
    } while (0)

    #define CAPTURE(k) do {                                      \
        bool cp = (g == (k));                                    \
        h1 = cp ? z1 : h1;                                       \
        h2 = cp ? z2 : h2;                                       \
    } while (0)

    // history regs: lane with g==k holds timeline entry (16*burst + k) of its
    // own chain; rows 2,3 duplicate rows 0,1 (not stored).
    float h1 = z1, h2 = z2;
    float* zp = zout + (size_t)b * TT * 2 + g * 2;
    const bool storer = (tid < 32);   // row0 -> chain0, row1 -> chain1

    // ---- prologue burst: entries 1..15 (h init covers entry 0 at g==0)
    #pragma unroll
    for (int k = 1; k < 16; ++k) { STEP(); CAPTURE(k); }
    if (storer) { float2 v; v.x = h1; v.y = h2; *(float2*)zp = v; }
    zp += 32;

    // ---- main loop: 255 bursts x 16 steps
    for (int bb = 1; bb < 256; ++bb) {
        #pragma unroll
        for (int k = 0; k < 16; ++k) { STEP(); CAPTURE(k); }
        if (storer) { float2 v; v.x = h1; v.y = h2; *(float2*)zp = v; }
        zp += 32;
    }
    #undef STEP
    #undef CAPTURE
}

// Kernel 2: streaming epilogue. Reads z (out2, L3-hot) + phi, writes a (out1)
// and xhat (out0). kappa = tanh(z); a = (k1*(1-k2), k2); xhat = a . phi.
__global__ __launch_bounds__(256) void finalize_kernel(
    const float* __restrict__ phi, const float* __restrict__ z,
    float* __restrict__ xhat, float* __restrict__ a)
{
    const int idx = blockIdx.x * blockDim.x + threadIdx.x;
    const int pos = idx * 2;                    // position pair (same b; t0 even)
    const int t0  = pos & (TT - 1);

    float4 zv = *(const float4*)(z   + (size_t)pos * 2);
    float4 pv = *(const float4*)(phi + (size_t)pos * 2);

    float k1a = tanh_fast(zv.x), k2a = tanh_fast(zv.y);
    float k1b = tanh_fast(zv.z), k2b = tanh_fast(zv.w);

    float a1a = k1a * (1.0f - k2a), a2a = k2a;
    float a1b = k1b * (1.0f - k2b), a2b = k2b;

    float4 av; av.x = a1a; av.y = a2a; av.z = a1b; av.w = a2b;
    *(float4*)(a + (size_t)pos * 2) = av;

    float x0 = (t0 >= 2)     ? fmaf(a2a, pv.y, a1a * pv.x) : 0.0f;
    float x1 = (t0 + 1 >= 2) ? fmaf(a2b, pv.w, a1b * pv.z) : 0.0f;
    float2 xv; xv.x = x0; xv.y = x1;
    *(float2*)(xhat + pos) = xv;
}

extern "C" void kernel_launch(void* const* d_in, const int* in_sizes, int n_in,
                              void* d_out, int out_size, void* d_ws, size_t ws_size,
                              hipStream_t stream) {
    const float* x    = (const float*)d_in[0];
    const float* phi  = (const float*)d_in[1];
    const float* ew1  = (const float*)d_in[2];
    const float* eb1  = (const float*)d_in[3];
    const float* ew2  = (const float*)d_in[4];
    const float* eb2  = (const float*)d_in[5];
    const float* fw1  = (const float*)d_in[6];
    const float* fb1  = (const float*)d_in[7];
    const float* fw2  = (const float*)d_in[8];
    const float* fb2  = (const float*)d_in[9];

    float* out  = (float*)d_out;
    float* xhat = out;                          // (B, T)
    float* a    = out + (size_t)BB * TT;        // (B, T, 2)
    float* z    = out + (size_t)BB * TT * 3;    // (B, T, 2)

    // 512 blocks x 64 threads: 1 wave/block, 2 chains/wave
    ode_scan_kernel<<<512, 64, 0, stream>>>(x, ew1, eb1, ew2, eb2,
                                            fw1, fb1, fw2, fb2, z);

    const int total_pairs = (BB * TT) / 2;
    finalize_kernel<<<total_pairs / 256, 256, 0, stream>>>(phi, z, xhat, a);
}